// Round 4
// baseline (144.934 us; speedup 1.0000x reference)
//
#include <hip/hip_runtime.h>
#include <math.h>

#define N       8192
#define BLK     256
#define JCHUNK  256                  // B-points staged per block
#define NSLICE  (N / JCHUNK)         // 32
#define ITILES  (N / BLK)            // 32
#define HALF    (ITILES * NSLICE)    // 1024 blocks per direction
#define GRID    (2 * HALF)           // 2048 = exactly 8 blocks/CU

// ---------------------------------------------------- precompute + init ----
// P[0..N)   = target packed {x,y,z,|p|^2};  P[N..2N) = output packed.
// dmin[0..2N) = +inf bits; cnt = 0.
__global__ __launch_bounds__(BLK) void chamfer_prep_kernel(
        const float* __restrict__ tgt, const float* __restrict__ outp,
        float4* __restrict__ P, unsigned* __restrict__ dmin,
        unsigned* __restrict__ cnt) {
    int i = blockIdx.x * BLK + (int)threadIdx.x;   // 0 .. 2N-1
    if (i == 0) cnt[0] = 0u;
    const float* src = (i < N) ? tgt : outp;
    int k = (i < N) ? i : (i - N);
    float x = src[3 * k + 0];
    float y = src[3 * k + 1];
    float z = src[3 * k + 2];
    P[i] = make_float4(x, y, z, fmaf(x, x, fmaf(y, y, z * z)));
    dmin[i] = 0x7F800000u;  // +inf
}

// ---------------------------------------------------------------- dist ----
// d^2 = |a|^2 + (|b|^2 - 2 a.b); the |a|^2 offset commutes with min.
// B-chunk staged in LDS, read via wave-uniform ds_read_b128 broadcast.
// Inner loop: 3 FMA + 1 min per pair, 8 independent accumulators.
// Last block to finish does the sqrt-mean reduction (fused, saves a launch).
__global__ __launch_bounds__(BLK) void chamfer_dist_kernel(
        const float4* __restrict__ P, unsigned* __restrict__ dmin,
        unsigned* __restrict__ cnt,
        const int* __restrict__ curp, const int* __restrict__ subp,
        float* __restrict__ out) {
    __shared__ float4 bl[JCHUNK];
    __shared__ int   lastf;
    __shared__ float red1[BLK / 64], red2[BLK / 64];

    int tid = (int)threadIdx.x;
    int bid = (int)blockIdx.x;
    int dir = (bid >= HALF) ? 1 : 0;
    if (dir) bid -= HALF;
    int aoff = dir ? N : 0;
    int boff = dir ? 0 : N;

    int itile = bid / NSLICE;
    int slice = bid % NSLICE;
    int i = itile * BLK + tid;

    // stage B-chunk: one coalesced b128 per thread
    bl[tid] = P[boff + slice * JCHUNK + tid];

    float4 a = P[aoff + i];
    float axm = -2.0f * a.x;
    float aym = -2.0f * a.y;
    float azm = -2.0f * a.z;

    __syncthreads();

    const float inf = __builtin_inff();
    float m0 = inf, m1 = inf, m2 = inf, m3 = inf;
    float m4 = inf, m5 = inf, m6 = inf, m7 = inf;

    for (int j = 0; j < JCHUNK; j += 8) {
        float4 b0 = bl[j + 0];
        float4 b1 = bl[j + 1];
        float4 b2 = bl[j + 2];
        float4 b3 = bl[j + 3];
        float4 b4 = bl[j + 4];
        float4 b5 = bl[j + 5];
        float4 b6 = bl[j + 6];
        float4 b7 = bl[j + 7];
        m0 = fminf(m0, fmaf(axm, b0.x, fmaf(aym, b0.y, fmaf(azm, b0.z, b0.w))));
        m1 = fminf(m1, fmaf(axm, b1.x, fmaf(aym, b1.y, fmaf(azm, b1.z, b1.w))));
        m2 = fminf(m2, fmaf(axm, b2.x, fmaf(aym, b2.y, fmaf(azm, b2.z, b2.w))));
        m3 = fminf(m3, fmaf(axm, b3.x, fmaf(aym, b3.y, fmaf(azm, b3.z, b3.w))));
        m4 = fminf(m4, fmaf(axm, b4.x, fmaf(aym, b4.y, fmaf(azm, b4.z, b4.w))));
        m5 = fminf(m5, fmaf(axm, b5.x, fmaf(aym, b5.y, fmaf(azm, b5.z, b5.w))));
        m6 = fminf(m6, fmaf(axm, b6.x, fmaf(aym, b6.y, fmaf(azm, b6.z, b6.w))));
        m7 = fminf(m7, fmaf(axm, b7.x, fmaf(aym, b7.y, fmaf(azm, b7.z, b7.w))));
    }
    float m = fminf(fminf(fminf(m0, m1), fminf(m2, m3)),
                    fminf(fminf(m4, m5), fminf(m6, m7)));
    float d2 = fmaxf(a.w + m, 0.0f);
    atomicMin(&dmin[aoff + i], __float_as_uint(d2));

    // ---- last block to finish: fused sqrt-mean reduction ----
    __threadfence();
    if (tid == 0) lastf = (atomicAdd(cnt, 1u) == (unsigned)(gridDim.x - 1));
    __syncthreads();
    if (!lastf) return;

    int wid = tid >> 6, lane = tid & 63;
    float s1 = 0.0f, s2 = 0.0f;
    for (int t = tid; t < N; t += BLK) {
        unsigned u1 = __hip_atomic_load(&dmin[t],     __ATOMIC_RELAXED, __HIP_MEMORY_SCOPE_AGENT);
        unsigned u2 = __hip_atomic_load(&dmin[N + t], __ATOMIC_RELAXED, __HIP_MEMORY_SCOPE_AGENT);
        s1 += sqrtf(__uint_as_float(u1));
        s2 += sqrtf(__uint_as_float(u2));
    }
    #pragma unroll
    for (int off = 32; off > 0; off >>= 1) {
        s1 += __shfl_down(s1, off, 64);
        s2 += __shfl_down(s2, off, 64);
    }
    if (lane == 0) { red1[wid] = s1; red2[wid] = s2; }
    __syncthreads();
    if (tid == 0) {
        float t1 = 0.0f, t2 = 0.0f;
        #pragma unroll
        for (int w = 0; w < BLK / 64; ++w) { t1 += red1[w]; t2 += red2[w]; }
        int e = curp[0] / subp[0];
        double scale = 10.0 / pow(0.99, (double)e);
        out[0] = (float)((((double)t1 + (double)t2) / (double)N) * 0.5 * scale);
    }
}

// ---------------------------------------------------------------- launch ----
extern "C" void kernel_launch(void* const* d_in, const int* in_sizes, int n_in,
                              void* d_out, int out_size, void* d_ws, size_t ws_size,
                              hipStream_t stream) {
    const float* target = (const float*)d_in[0];   // (1, 8192, 3) f32
    const float* output = (const float*)d_in[1];   // (1, 8192, 3) f32
    const int*   curp   = (const int*)d_in[2];
    const int*   subp   = (const int*)d_in[3];
    float* out = (float*)d_out;

    // ws: float4 P[2N] (256 KB) | uint dmin[2N] (64 KB) | uint cnt
    float4*   P    = (float4*)d_ws;
    unsigned* dmin = (unsigned*)(P + 2 * N);
    unsigned* cnt  = dmin + 2 * N;

    chamfer_prep_kernel<<<2 * N / BLK, BLK, 0, stream>>>(target, output, P, dmin, cnt);
    chamfer_dist_kernel<<<GRID, BLK, 0, stream>>>(P, dmin, cnt, curp, subp, out);
}

// Round 5
// 78.535 us; speedup vs baseline: 1.8455x; 1.8455x over previous
//
#include <hip/hip_runtime.h>
#include <math.h>

#define N        8192
#define BLK      256
#define RPT      4                     // rows (a-points) per thread
#define ROWS_BLK (BLK * RPT)           // 1024 rows per block
#define G        (N / ROWS_BLK)        // 8 row-groups per direction
#define S        32                    // j-slices per direction
#define JC       (N / S)               // 256 b-points per slice
#define HALF     (G * S)               // 256 blocks per direction
#define GRID     (2 * HALF)            // 512 blocks = 2/CU

// ---------------------------------------------------- precompute + init ----
// P[0..N) = target packed {x,y,z,|p|^2}; P[N..2N) = output packed.
// dmin[0..2N) = +inf bits; cnt = 0.
__global__ __launch_bounds__(BLK) void chamfer_prep_kernel(
        const float* __restrict__ tgt, const float* __restrict__ outp,
        float4* __restrict__ P, unsigned* __restrict__ dmin,
        unsigned* __restrict__ cnt) {
    int i = blockIdx.x * BLK + (int)threadIdx.x;   // 0 .. 2N-1
    if (i == 0) cnt[0] = 0u;
    const float* src = (i < N) ? tgt : outp;
    int k = (i < N) ? i : (i - N);
    float x = src[3 * k + 0];
    float y = src[3 * k + 1];
    float z = src[3 * k + 2];
    P[i] = make_float4(x, y, z, fmaf(x, x, fmaf(y, y, z * z)));
    dmin[i] = 0x7F800000u;  // +inf
}

// ---------------------------------------------------------------- dist ----
// d^2 = |a|^2 + (|b|^2 - 2 a.b); |a|^2 offset commutes with min.
// B-points fetched once per WAVE via wave-uniform s_load_dwordx4 (scalar
// cache, separate pipe) and shared by 4 rows/thread -> 16 VALU ops per
// 16-byte fetch. Inner loop cost: 4 VALU ops/pair.
__global__ __launch_bounds__(BLK) void chamfer_dist_kernel(
        const float4* __restrict__ P, unsigned* __restrict__ dmin,
        unsigned* __restrict__ cnt,
        const int* __restrict__ curp, const int* __restrict__ subp,
        float* __restrict__ out) {
    __shared__ int   lastf;
    __shared__ float red1[BLK / 64], red2[BLK / 64];

    int tid = (int)threadIdx.x;
    int bid = (int)blockIdx.x;
    int dir = (bid >= HALF) ? 1 : 0;
    if (dir) bid -= HALF;
    int aoff = dir ? N : 0;
    int boff = dir ? 0 : N;

    int rg = bid % G;          // row-group
    int sl = bid / G;          // j-slice
    int row0 = rg * ROWS_BLK + tid;   // rows: row0 + k*BLK, k<RPT (strided)

    float axm[RPT], aym[RPT], azm[RPT], a2[RPT];
    #pragma unroll
    for (int k = 0; k < RPT; ++k) {
        float4 a = P[aoff + row0 + k * BLK];   // coalesced
        axm[k] = -2.0f * a.x;
        aym[k] = -2.0f * a.y;
        azm[k] = -2.0f * a.z;
        a2[k]  = a.w;
    }

    const float inf = __builtin_inff();
    float m0[RPT], m1[RPT];
    #pragma unroll
    for (int k = 0; k < RPT; ++k) { m0[k] = inf; m1[k] = inf; }

    const float4* __restrict__ bp = P + boff + sl * JC;   // wave-uniform
    for (int j = 0; j < JC; j += 4) {
        float4 b0 = bp[j + 0];
        float4 b1 = bp[j + 1];
        float4 b2 = bp[j + 2];
        float4 b3 = bp[j + 3];
        #pragma unroll
        for (int k = 0; k < RPT; ++k) {
            m0[k] = fminf(m0[k], fmaf(axm[k], b0.x, fmaf(aym[k], b0.y, fmaf(azm[k], b0.z, b0.w))));
            m1[k] = fminf(m1[k], fmaf(axm[k], b1.x, fmaf(aym[k], b1.y, fmaf(azm[k], b1.z, b1.w))));
            m0[k] = fminf(m0[k], fmaf(axm[k], b2.x, fmaf(aym[k], b2.y, fmaf(azm[k], b2.z, b2.w))));
            m1[k] = fminf(m1[k], fmaf(axm[k], b3.x, fmaf(aym[k], b3.y, fmaf(azm[k], b3.z, b3.w))));
        }
    }
    #pragma unroll
    for (int k = 0; k < RPT; ++k) {
        float d2 = fmaxf(a2[k] + fminf(m0[k], m1[k]), 0.0f);
        atomicMin(&dmin[aoff + row0 + k * BLK], __float_as_uint(d2));  // coalesced
    }

    // ---- last block to finish: fused sqrt-mean reduction ----
    __threadfence();
    if (tid == 0) lastf = (atomicAdd(cnt, 1u) == (unsigned)(gridDim.x - 1));
    __syncthreads();
    if (!lastf) return;

    int wid = tid >> 6, lane = tid & 63;
    float s1 = 0.0f, s2 = 0.0f;
    for (int t = tid; t < N; t += BLK) {
        unsigned u1 = __hip_atomic_load(&dmin[t],     __ATOMIC_RELAXED, __HIP_MEMORY_SCOPE_AGENT);
        unsigned u2 = __hip_atomic_load(&dmin[N + t], __ATOMIC_RELAXED, __HIP_MEMORY_SCOPE_AGENT);
        s1 += sqrtf(__uint_as_float(u1));
        s2 += sqrtf(__uint_as_float(u2));
    }
    #pragma unroll
    for (int off = 32; off > 0; off >>= 1) {
        s1 += __shfl_down(s1, off, 64);
        s2 += __shfl_down(s2, off, 64);
    }
    if (lane == 0) { red1[wid] = s1; red2[wid] = s2; }
    __syncthreads();
    if (tid == 0) {
        float t1 = 0.0f, t2 = 0.0f;
        #pragma unroll
        for (int w = 0; w < BLK / 64; ++w) { t1 += red1[w]; t2 += red2[w]; }
        int e = curp[0] / subp[0];
        double scale = 10.0 / pow(0.99, (double)e);
        out[0] = (float)((((double)t1 + (double)t2) / (double)N) * 0.5 * scale);
    }
}

// ---------------------------------------------------------------- launch ----
extern "C" void kernel_launch(void* const* d_in, const int* in_sizes, int n_in,
                              void* d_out, int out_size, void* d_ws, size_t ws_size,
                              hipStream_t stream) {
    const float* target = (const float*)d_in[0];   // (1, 8192, 3) f32
    const float* output = (const float*)d_in[1];   // (1, 8192, 3) f32
    const int*   curp   = (const int*)d_in[2];
    const int*   subp   = (const int*)d_in[3];
    float* out = (float*)d_out;

    // ws: float4 P[2N] (256 KB) | uint dmin[2N] (64 KB) | uint cnt
    float4*   P    = (float4*)d_ws;
    unsigned* dmin = (unsigned*)(P + 2 * N);
    unsigned* cnt  = dmin + 2 * N;

    chamfer_prep_kernel<<<2 * N / BLK, BLK, 0, stream>>>(target, output, P, dmin, cnt);
    chamfer_dist_kernel<<<GRID, BLK, 0, stream>>>(P, dmin, cnt, curp, subp, out);
}